// Round 10
// baseline (764.846 us; speedup 1.0000x reference)
//
#include <hip/hip_runtime.h>
#include <hip/hip_bf16.h>

#define DI __device__ __forceinline__

typedef __attribute__((ext_vector_type(8))) short short8;
typedef __attribute__((ext_vector_type(4))) float f32x4;

DI unsigned short f2bf(float f) {
    union { float f; unsigned int u; } v; v.f = f;
    unsigned int r = v.u + 0x7FFFu + ((v.u >> 16) & 1u);
    return (unsigned short)(r >> 16);
}
DI float bf2f(unsigned short h) {
    union { unsigned int u; float f; } v; v.u = ((unsigned int)h) << 16;
    return v.f;
}

#define GLD16(g, l) __builtin_amdgcn_global_load_lds( \
    (const __attribute__((address_space(1))) void*)(g), \
    (__attribute__((address_space(3))) void*)(l), 16, 0, 0)

// ---------------------------------------------------------------------------
// 256x256 NT GEMM, 256 threads = 4 waves (2x2), 128x128 PER WAVE (acc[8][8],
// 256 VGPR), K=32 regions in a 4-slot rotation, 128KiB LDS.
// Rationale (r10): r9 was LDS-read-BW bound (12 b128/wave/phase at 8 waves =
// 98KB/CU/phase ~ 1150cyc > 620cyc MFMA -> 54% cap). 128x128/wave: 16 reads
// per 64 MFMAs = -33% LDS B/FLOP; per-SIMD MFMA 1240cyc > LDS 585cyc -> MFMA
// becomes critical path. 1 wave/SIMD; staging hidden by 3-region lead.
// Swizzle (verified r4-r9): LDS[r][p] = G[r][p ^ ((r>>1)&3)].
// XCD chunking (bijective, nwg%8==0): lin -> (lin&7)*(nwg/8)+(lin>>3).
// Region slot s at lds[s*16384]: A-half 256x32 at +0, B-half 256x32 at +8192.
// 8 loads/region; vmcnt(16) per phase (3 regions in flight); peel 16->8->0.
// NT full-line stores for write-once outputs (EPI0 via LDS-transpose, EPI3
// direct f32) -- r9-verified.
// EPI: 0 = +bias->bf16(NT), 1 = *scale+mask->bf16, 2 = bf16, 3 = +bias->f32(NT)
// QKV=1: tn in [0,15); g = tn/5 selects Bt/Cout/bias.
// Requires: M%256==0, N%256==0, K%128==0, K>=256.
// ---------------------------------------------------------------------------
template<int EPI, int QKV>
__global__ __launch_bounds__(256, 1) void gemm256(
    const unsigned short* __restrict__ A, const unsigned short* __restrict__ Bt,
    void* __restrict__ Cout, const float* __restrict__ bias,
    const float* __restrict__ bias1, const float* __restrict__ bias2,
    const int* __restrict__ mask, int K, int lda, int ldb, int ldc,
    long sA, long sB, long sC, long sM, float scale)
{
    __shared__ unsigned short lds[65536];   // 128 KiB = 4 slots x 32KB

    // XCD-chunked bijective remap of the flattened grid (nwg % 8 == 0)
    const unsigned gx = gridDim.x, gy = gridDim.y;
    unsigned lin = blockIdx.x + gx * (blockIdx.y + gy * blockIdx.z);
    const unsigned nwg = gx * gy * gridDim.z;
    lin = (lin & 7u) * (nwg >> 3) + (lin >> 3);
    int tn = lin % gx;
    const int tm = (lin / gx) % gy;
    const int z = lin / (gx * gy);

    if (QKV) {
        const int g = tn / 5; tn -= g * 5;
        Bt += (size_t)g * sB;
        Cout = (void*)((unsigned short*)Cout + (size_t)g * sC);
        if (g == 1) bias = bias1; else if (g == 2) bias = bias2;
    }

    const unsigned short* Ab = A + (long)z * sA + (size_t)(tm * 256) * lda;
    const unsigned short* Bb = Bt + (QKV ? 0 : (long)z * sB) + (size_t)(tn * 256) * ldb;

    const int tid = threadIdx.x, wave = tid >> 6, l = tid & 63;
    const int wr = wave >> 1, wc = wave & 1;    // 2 x 2 wave grid

    // staging: per round a wave covers 16 rows (lane l -> row w*16 + (l>>2),
    // chunk l&3); 4 rounds advance rows by 64. Source chunk pre-swizzled:
    // LDS[r][p] = G[r][p ^ ((r>>1)&3)]; row = w*16 + (l>>2) -> swz = (l>>3)&3.
    const int schunk = ((l & 3) ^ ((l >> 3) & 3)) * 8;
    const unsigned short* agS = Ab + (size_t)(wave * 16 + (l >> 2)) * lda + schunk;
    const unsigned short* bgS = Bb + (size_t)(wave * 16 + (l >> 2)) * ldb + schunk;
    unsigned short* ldsA = &lds[wave * 512];
    unsigned short* ldsB = &lds[8192 + wave * 512];

    // ds_read offsets; row = mult16 + (l&15) -> swz = (l>>1)&3
    const int rl = l & 15;
    const int cl8 = ((l >> 4) ^ ((l >> 1) & 3)) * 8;
    const int aoff = (wr * 128 + rl) * 32 + cl8;
    const int boff = 8192 + (wc * 128 + rl) * 32 + cl8;

#define SLOTOFF(s) ((s) * 16384)
#define SA4(t, s) { const unsigned short* g_ = agS + (size_t)(t) * 32; \
    GLD16(g_,                      ldsA + SLOTOFF(s)); \
    GLD16(g_ + (size_t)64 * lda,   ldsA + SLOTOFF(s) + 2048); \
    GLD16(g_ + (size_t)128 * lda,  ldsA + SLOTOFF(s) + 4096); \
    GLD16(g_ + (size_t)192 * lda,  ldsA + SLOTOFF(s) + 6144); }
#define SB4(t, s) { const unsigned short* g_ = bgS + (size_t)(t) * 32; \
    GLD16(g_,                      ldsB + SLOTOFF(s)); \
    GLD16(g_ + (size_t)64 * ldb,   ldsB + SLOTOFF(s) + 2048); \
    GLD16(g_ + (size_t)128 * ldb,  ldsB + SLOTOFF(s) + 4096); \
    GLD16(g_ + (size_t)192 * ldb,  ldsB + SLOTOFF(s) + 6144); }

    f32x4 acc[8][8] = {};

    // One phase: consume slot s (K=32, 64 MFMA/wave), stage region, 1 barrier.
    // Read order af[0..3], bfv[0..7], af[4..7]; lgkmcnt(4) -> first 12 done.
#define PHASE(s, STG, VMW) { \
    short8 af[8], bfv[8]; \
    _Pragma("unroll") for (int i = 0; i < 4; ++i) \
        af[i] = *(const short8*)&lds[SLOTOFF(s) + aoff + i * 512]; \
    _Pragma("unroll") for (int n = 0; n < 8; ++n) \
        bfv[n] = *(const short8*)&lds[SLOTOFF(s) + boff + n * 512]; \
    _Pragma("unroll") for (int i = 4; i < 8; ++i) \
        af[i] = *(const short8*)&lds[SLOTOFF(s) + aoff + i * 512]; \
    STG; \
    asm volatile("s_waitcnt lgkmcnt(4)" ::: "memory"); \
    __builtin_amdgcn_sched_barrier(0); \
    __builtin_amdgcn_s_setprio(1); \
    _Pragma("unroll") for (int i = 0; i < 4; ++i) \
        _Pragma("unroll") for (int n = 0; n < 8; ++n) \
            acc[i][n] = __builtin_amdgcn_mfma_f32_16x16x32_bf16( \
                af[i], bfv[n], acc[i][n], 0, 0, 0); \
    asm volatile("s_waitcnt lgkmcnt(0)" ::: "memory"); \
    __builtin_amdgcn_sched_barrier(0); \
    _Pragma("unroll") for (int i = 4; i < 8; ++i) \
        _Pragma("unroll") for (int n = 0; n < 8; ++n) \
            acc[i][n] = __builtin_amdgcn_mfma_f32_16x16x32_bf16( \
                af[i], bfv[n], acc[i][n], 0, 0, 0); \
    __builtin_amdgcn_s_setprio(0); \
    asm volatile("s_waitcnt " VMW ::: "memory"); \
    __builtin_amdgcn_s_barrier(); \
  }

    // prologue: stage regions 0,1,2 (24 loads); vmcnt(16) -> region 0 ready
    SA4(0, 0) SB4(0, 0) SA4(1, 1) SB4(1, 1) SA4(2, 2) SB4(2, 2)
    asm volatile("s_waitcnt vmcnt(16)" ::: "memory");
    __builtin_amdgcn_s_barrier();

    const int NR = K >> 5;          // K=32 regions; NR % 4 == 0
    for (int j = 0; j < (NR >> 2) - 1; ++j) {
        const int t = 4 * j;
        PHASE(0, SA4(t + 3, 3) SB4(t + 3, 3), "vmcnt(16)")
        PHASE(1, SA4(t + 4, 0) SB4(t + 4, 0), "vmcnt(16)")
        PHASE(2, SA4(t + 5, 1) SB4(t + 5, 1), "vmcnt(16)")
        PHASE(3, SA4(t + 6, 2) SB4(t + 6, 2), "vmcnt(16)")
    }
    {   // peeled last 4 phases: stage final region, drain 16->8->0->0
        const int t = NR - 4;
        PHASE(0, SA4(t + 3, 3) SB4(t + 3, 3), "vmcnt(16)")
        PHASE(1, ((void)0),                   "vmcnt(8)")
        PHASE(2, ((void)0),                   "vmcnt(0)")
        PHASE(3, ((void)0),                   "vmcnt(0)")
    }
#undef PHASE
#undef SA4
#undef SB4
#undef SLOTOFF

    // ---------------- epilogue ----------------
    const long cb = QKV ? 0 : (long)z * sC;
    const int row0 = tm * 256 + wr * 128 + (l >> 4) * 4;
    const int col0 = tn * 256 + wc * 128 + rl;

    if (EPI == 0) {
        // LDS-transpose + 16B nontemporal stores (full-line NT, no L3 fill)
        float b8[8];
        #pragma unroll
        for (int n = 0; n < 8; ++n) b8[n] = bias[col0 + n * 16];
        unsigned short* gout = (unsigned short*)Cout;
        #pragma unroll
        for (int half = 0; half < 2; ++half) {
            if (wr == half) {
                #pragma unroll
                for (int mi = 0; mi < 8; ++mi)
                    #pragma unroll
                    for (int n = 0; n < 8; ++n)
                        #pragma unroll
                        for (int r = 0; r < 4; ++r) {
                            const int lr = mi * 16 + ((l >> 4) << 2) + r;
                            const int lc = wc * 128 + n * 16 + rl;
                            lds[lr * 264 + lc] = f2bf(acc[mi][n][r] + b8[n]);
                        }
            }
            __syncthreads();
            const long rbase = (long)(tm * 256 + half * 128);
            #pragma unroll
            for (int rr = 0; rr < 16; ++rr) {
                const int row = rr * 8 + (tid >> 5);
                const int ch = tid & 31;
                short8 vv = *(const short8*)&lds[row * 264 + ch * 8];
                __builtin_nontemporal_store(vv,
                    (short8*)&gout[(rbase + row) * (size_t)ldc + tn * 256 + ch * 8]);
            }
            __syncthreads();
        }
    } else {
        #pragma unroll
        for (int mi = 0; mi < 8; ++mi) {
            #pragma unroll
            for (int n = 0; n < 8; ++n) {
                #pragma unroll
                for (int r = 0; r < 4; ++r) {
                    const int row = row0 + mi * 16 + r;
                    const int col = col0 + n * 16;
                    float v = acc[mi][n][r];
                    if (EPI == 3) v += bias[col];
                    if (EPI == 1) {
                        v *= scale;
                        if (mask[(long)z * sM + (long)row * ldc + col] == 0)
                            v = -1e20f * scale;
                    }
                    if (EPI == 3)   // f32: 16 lanes x 4B = full 64B line -> NT ok
                        __builtin_nontemporal_store(v, &((float*)Cout)[cb + (long)row * ldc + col]);
                    else
                        ((unsigned short*)Cout)[cb + (long)row * ldc + col] = f2bf(v);
                }
            }
        }
    }
}

// ---------------------------------------------------------------------------
// Transpose+cast the four 1280x1280 f32 weights -> Wt[j][k] bf16
// ---------------------------------------------------------------------------
__global__ void transpose_w(const float* __restrict__ Wq, const float* __restrict__ Wk,
                            const float* __restrict__ Wv, const float* __restrict__ Wr,
                            unsigned short* __restrict__ Wt)
{
    const float* W = blockIdx.z == 0 ? Wq : blockIdx.z == 1 ? Wk : blockIdx.z == 2 ? Wv : Wr;
    unsigned short* dst = Wt + (size_t)blockIdx.z * 1280 * 1280;
    __shared__ float T[64][65];
    const int j0 = blockIdx.x * 64, k0 = blockIdx.y * 64;
    const int tid = threadIdx.x;
    for (int it = 0; it < 16; ++it) {
        int idx = it * 256 + tid;
        int r = idx >> 6, c = idx & 63;
        T[r][c] = W[(size_t)(k0 + r) * 1280 + j0 + c];
    }
    __syncthreads();
    for (int it = 0; it < 16; ++it) {
        int idx = it * 256 + tid;
        int r = idx >> 6, c = idx & 63;
        dst[(size_t)(j0 + r) * 1280 + k0 + c] = f2bf(T[c][r]);
    }
}

// ---------------------------------------------------------------------------
// Cast x f32 -> bf16, vectorized
// ---------------------------------------------------------------------------
__global__ void cast_x(const float* __restrict__ x, unsigned short* __restrict__ xb, long n)
{
    long i = ((long)blockIdx.x * 256 + threadIdx.x) * 8;
    if (i + 8 > n) return;
    const float4* p = (const float4*)(x + i);
    float4 a = p[0], b = p[1];
    unsigned short o[8] = { f2bf(a.x), f2bf(a.y), f2bf(a.z), f2bf(a.w),
                            f2bf(b.x), f2bf(b.y), f2bf(b.z), f2bf(b.w) };
    *(short8*)(xb + i) = *(short8*)o;
}

// ---------------------------------------------------------------------------
// Row softmax of scaled+masked scores S'[b][m][n] (bf16) and transposed write
// Pt[b][n][m] = softmax_row(S')[m][n].  One block per (64-row strip, batch).
// ---------------------------------------------------------------------------
#define SMS 514
__global__ void softmax_t(const unsigned short* __restrict__ S, unsigned short* __restrict__ Pt)
{
    __shared__ unsigned short T[64 * SMS];
    __shared__ float rmax[64], rinv[64];
    const int b = blockIdx.y, mb = blockIdx.x * 64;
    const int tid = threadIdx.x, lane = tid & 63, wave = tid >> 6;
    const unsigned short* src = S + ((size_t)b * 512 + mb) * 512;

    for (int rr = 0; rr < 16; ++rr) {
        int r = rr * 4 + wave;
        const unsigned int* s = (const unsigned int*)(src + (size_t)r * 512);
        unsigned int* t = (unsigned int*)&T[r * SMS];
        #pragma unroll
        for (int j = 0; j < 4; ++j) t[lane + j * 64] = s[lane + j * 64];
    }
    __syncthreads();

    {   // row stats: 4 threads per row
        int r = tid >> 2, q = tid & 3;
        const unsigned short* row = &T[r * SMS + q * 128];
        float mx = -3.0e38f;
        for (int i = 0; i < 128; ++i) mx = fmaxf(mx, bf2f(row[i]));
        mx = fmaxf(mx, __shfl_xor(mx, 1));
        mx = fmaxf(mx, __shfl_xor(mx, 2));
        float s = 0.f;
        for (int i = 0; i < 128; ++i) s += expf(bf2f(row[i]) - mx);
        s += __shfl_xor(s, 1);
        s += __shfl_xor(s, 2);
        if (q == 0) { rmax[r] = mx; rinv[r] = 1.0f / s; }
    }
    __syncthreads();

    {   // transposed write: lane -> m, groups of 64 -> n
        int m = tid & 63, nq = tid >> 6;
        float mxm = rmax[m], rim = rinv[m];
        unsigned short* dst = Pt + (size_t)b * 512 * 512 + mb + m;
        for (int it = 0; it < 128; ++it) {
            int n = it * 4 + nq;
            float v = expf(bf2f(T[m * SMS + n]) - mxm) * rim;
            dst[(size_t)n * 512] = f2bf(v);
        }
    }
}

// ---------------------------------------------------------------------------
// Per-batch transpose V[b][m][c] -> Vt[b][c][m]  (bf16)
// ---------------------------------------------------------------------------
__global__ void transpose_v(const unsigned short* __restrict__ V, unsigned short* __restrict__ Vt)
{
    __shared__ unsigned short T[64][65];
    const int b = blockIdx.z;
    const int c0 = blockIdx.x * 64, m0 = blockIdx.y * 64;
    const int tid = threadIdx.x;
    const unsigned short* src = V + ((size_t)b * 512 + m0) * 1280 + c0;
    for (int it = 0; it < 16; ++it) {
        int idx = it * 256 + tid;
        int r = idx >> 6, c = idx & 63;
        T[r][c] = src[(size_t)r * 1280 + c];
    }
    __syncthreads();
    unsigned short* dst = Vt + ((size_t)b * 1280 + c0) * 512 + m0;
    for (int it = 0; it < 16; ++it) {
        int idx = it * 256 + tid;
        int r = idx >> 6, c = idx & 63;
        dst[(size_t)r * 512 + c] = T[c][r];
    }
}

// ---------------------------------------------------------------------------
extern "C" void kernel_launch(void* const* d_in, const int* in_sizes, int n_in,
                              void* d_out, int out_size, void* d_ws, size_t ws_size,
                              hipStream_t stream)
{
    const float* x   = (const float*)d_in[0];
    const int*  Mask = (const int*)d_in[1];
    const float* Wq  = (const float*)d_in[2];
    const float* bq  = (const float*)d_in[3];
    const float* Wk  = (const float*)d_in[4];
    const float* bk  = (const float*)d_in[5];
    const float* Wv  = (const float*)d_in[6];
    const float* bv  = (const float*)d_in[7];
    const float* Wr  = (const float*)d_in[8];
    const float* br  = (const float*)d_in[9];

    constexpr int N = 512, C = 1280;
    constexpr long MN = 32768;   // B*N

    char* ws = (char*)d_ws;
    unsigned short* xb = (unsigned short*)ws;                         // MN*C bf16 (later: att)
    unsigned short* Wt = (unsigned short*)(ws + 83886080);            // 4*C*C bf16
    unsigned short* Q  = (unsigned short*)(ws + 83886080 + 13107200); // MN*C (later: Vt)
    unsigned short* Km = Q + 41943040;
    unsigned short* V  = Km + 41943040;
    unsigned short* Sp = V + 41943040;                                // B*N*N
    unsigned short* Pt = Sp + 16777216;                               // B*N*N
    unsigned short* Vt = Q;     // alias: Q dead after scores GEMM
    unsigned short* att = xb;   // alias: xb dead after QKV GEMMs

    const float scale = 0.02795084971874737f;   // 1/sqrt(1280)

    transpose_w<<<dim3(20, 20, 4), 256, 0, stream>>>(Wq, Wk, Wv, Wr, Wt);
    cast_x<<<dim3(20480), 256, 0, stream>>>(x, xb, MN * C);

    // fused QKV projections: M=32768, N=3x1280, K=1280; tn/5 selects group
    gemm256<0, 1><<<dim3(15, 128, 1), 256, 0, stream>>>(xb, Wt, (void*)Q, bq, bk, bv,
        nullptr, C, C, C, C, 0, 1638400L, 41943040L, 0, 0.f);

    // scores: S'[b][i][j] = scale * (Q[b][i] . K[b][j]), masked
    gemm256<1, 0><<<dim3(2, 2, 64), 256, 0, stream>>>(Q, Km, (void*)Sp, nullptr, nullptr, nullptr,
        Mask, C, C, C, N, (long)N * C, (long)N * C, (long)N * N, (long)N * N, scale);

    // softmax rows + transposed store Pt[b][n][m]
    softmax_t<<<dim3(8, 64), 256, 0, stream>>>(Sp, Pt);

    // Vt[b][c][m]
    transpose_v<<<dim3(20, 8, 64), 256, 0, stream>>>(V, Vt);

    // att[b][n][c] = sum_m Pt[b][n][m] * Vt[b][c][m]   (M=512, N=1280, K=512)
    gemm256<2, 0><<<dim3(5, 2, 64), 256, 0, stream>>>(Pt, Vt, (void*)att, nullptr, nullptr, nullptr,
        nullptr, N, N, N, C, (long)N * N, (long)C * N, (long)N * C, 0, 0.f);

    // out = att @ Wr + br   (f32)
    gemm256<3, 0><<<dim3(5, 128, 1), 256, 0, stream>>>(att, Wt + 3 * 1638400, d_out, br, nullptr, nullptr,
        nullptr, C, C, C, C, 0, 0, 0, 0, 0.f);
}

// Round 11
// 697.367 us; speedup vs baseline: 1.0968x; 1.0968x over previous
//
#include <hip/hip_runtime.h>
#include <hip/hip_bf16.h>

#define DI __device__ __forceinline__

typedef __attribute__((ext_vector_type(8))) short short8;
typedef __attribute__((ext_vector_type(4))) float f32x4;

DI unsigned short f2bf(float f) {
    union { float f; unsigned int u; } v; v.f = f;
    unsigned int r = v.u + 0x7FFFu + ((v.u >> 16) & 1u);
    return (unsigned short)(r >> 16);
}
DI float bf2f(unsigned short h) {
    union { unsigned int u; float f; } v; v.u = ((unsigned int)h) << 16;
    return v.f;
}

#define GLD16(g, l) __builtin_amdgcn_global_load_lds( \
    (const __attribute__((address_space(1))) void*)(g), \
    (__attribute__((address_space(3))) void*)(l), 16, 0, 0)

// ---------------------------------------------------------------------------
// 256x256 4-phase NT GEMM, BK=64, 8 waves (2Mx4N), 128KiB LDS.
// C[i][j] = sum_k A[i][k] * Bt[j][k]
// r11 change vs r9 (the 699us best): REMOVE the manual lgkmcnt(4)/lgkmcnt(0)
// + sched_barrier(0) pins inside the phase. r9 forced {12-read burst -> wait
// -> 32 MFMA} lockstep across all waves (LDS pipe saturated while MFMA idle,
// then vice versa -> 45% cap). The compiler emits fine-grained lgkmcnt(N)
// between each ds_read and its dependent MFMA (m97 evidence), interleaving
// the two pipes. Hand-written waits kept ONLY for the staging ledger:
// vmcnt(N) + barrier at phase end (RAW/WAR across waves), exactly as r9.
// Swizzle (conflict-free, r4-r9): LDS[r][p] = G[r][p ^ ((r>>1)&3)].
// XCD chunking (bijective, nwg%8==0): lin -> (lin&7)*(nwg/8)+(lin>>3).
// NT full-line stores for write-once outputs (EPI0 LDS-transpose, EPI3 f32).
// EPI: 0 = +bias->bf16(NT), 1 = *scale+mask->bf16, 2 = bf16, 3 = +bias->f32(NT)
// QKV=1: tn in [0,15); g = tn/5 selects Bt/Cout/bias.
// Requires: M%256==0, N%256==0, K%128==0, K>=256.
// ---------------------------------------------------------------------------
template<int EPI, int QKV>
__global__ __launch_bounds__(512, 2) void gemm256(
    const unsigned short* __restrict__ A, const unsigned short* __restrict__ Bt,
    void* __restrict__ Cout, const float* __restrict__ bias,
    const float* __restrict__ bias1, const float* __restrict__ bias2,
    const int* __restrict__ mask, int K, int lda, int ldb, int ldc,
    long sA, long sB, long sC, long sM, float scale)
{
    __shared__ unsigned short lds[65536];   // 128 KiB

    // XCD-chunked bijective remap of the flattened grid (nwg % 8 == 0)
    const unsigned gx = gridDim.x, gy = gridDim.y;
    unsigned lin = blockIdx.x + gx * (blockIdx.y + gy * blockIdx.z);
    const unsigned nwg = gx * gy * gridDim.z;
    lin = (lin & 7u) * (nwg >> 3) + (lin >> 3);
    int tn = lin % gx;
    const int tm = (lin / gx) % gy;
    const int z = lin / (gx * gy);

    if (QKV) {
        const int g = tn / 5; tn -= g * 5;
        Bt += (size_t)g * sB;
        Cout = (void*)((unsigned short*)Cout + (size_t)g * sC);
        if (g == 1) bias = bias1; else if (g == 2) bias = bias2;
    }

    const unsigned short* Ab = A + (long)z * sA + (size_t)(tm * 256) * lda;
    const unsigned short* Bb = Bt + (QKV ? 0 : (long)z * sB) + (size_t)(tn * 256) * ldb;

    const int tid = threadIdx.x, wave = tid >> 6, l = tid & 63;
    const int wr = wave >> 2, wc = wave & 3;    // 2 x 4 wave grid

    const int srow = wave * 32 + (l >> 2);
    const int schunk = ((l & 3) ^ ((l >> 3) & 3)) * 8;
    const unsigned short* agS = Ab + (size_t)srow * lda + schunk;
    const unsigned short* bgS = Bb + (size_t)srow * ldb + schunk;
    unsigned short* ldsA0 = &lds[wave * 1024];
    unsigned short* ldsB0 = &lds[8192 + wave * 1024];

    const int rl = l & 15;
    const int cl8 = ((l >> 4) ^ ((l >> 1) & 3)) * 8;
    const int aoff = (wr * 128 + rl) * 32 + cl8;
    const int boff = 8192 + (wc * 64 + rl) * 32 + cl8;

#define REGOFF(buf, h) (((buf) * 2 + (h)) * 16384)
#define SA(t, h, buf) { const unsigned short* g_ = agS + (size_t)((t) * 64 + (h) * 32); \
    GLD16(g_, ldsA0 + REGOFF(buf, h)); \
    GLD16(g_ + (size_t)16 * lda, ldsA0 + REGOFF(buf, h) + 512); }
#define SB(t, h, buf) { const unsigned short* g_ = bgS + (size_t)((t) * 64 + (h) * 32); \
    GLD16(g_, ldsB0 + REGOFF(buf, h)); \
    GLD16(g_ + (size_t)16 * ldb, ldsB0 + REGOFF(buf, h) + 512); }

    f32x4 acc[8][4] = {};

    // One phase: consume region (buf,h) fully (32 MFMA), stage next, 1 barrier.
    // No manual lgkm waits: compiler interleaves ds_reads with MFMAs via its
    // own fine-grained lgkmcnt. vmcnt(N)+barrier keep the staging ledger.
#define PHASE(buf, h, STG, VMW) { \
    short8 af[8], bfv[4]; \
    _Pragma("unroll") for (int i = 0; i < 4; ++i) \
        af[i] = *(const short8*)&lds[REGOFF(buf, h) + aoff + i * 512]; \
    _Pragma("unroll") for (int n = 0; n < 4; ++n) \
        bfv[n] = *(const short8*)&lds[REGOFF(buf, h) + boff + n * 512]; \
    _Pragma("unroll") for (int i = 4; i < 8; ++i) \
        af[i] = *(const short8*)&lds[REGOFF(buf, h) + aoff + i * 512]; \
    STG; \
    __builtin_amdgcn_s_setprio(1); \
    _Pragma("unroll") for (int i = 0; i < 8; ++i) \
        _Pragma("unroll") for (int n = 0; n < 4; ++n) \
            acc[i][n] = __builtin_amdgcn_mfma_f32_16x16x32_bf16( \
                af[i], bfv[n], acc[i][n], 0, 0, 0); \
    __builtin_amdgcn_s_setprio(0); \
    asm volatile("s_waitcnt " VMW ::: "memory"); \
    __builtin_amdgcn_s_barrier(); \
  }

    // prologue: buf0h0, buf0h1, buf1h0 (12 loads); wait buf0h0 (oldest 4)
    SA(0, 0, 0); SB(0, 0, 0); SA(0, 1, 0); SB(0, 1, 0); SA(1, 0, 1); SB(1, 0, 1);
    asm volatile("s_waitcnt vmcnt(8)" ::: "memory");
    __builtin_amdgcn_s_barrier();

    const int NI = K >> 7;          // iterations, 2 K-tiles (BK=64) each
    for (int j = 0; j < NI - 1; ++j) {
        const int t = 2 * j;
        PHASE(0, 0, SA(t + 1, 1, 1) SB(t + 1, 1, 1), "vmcnt(8)")
        PHASE(0, 1, SA(t + 2, 0, 0) SB(t + 2, 0, 0), "vmcnt(8)")
        PHASE(1, 0, SA(t + 2, 1, 0) SB(t + 2, 1, 0), "vmcnt(8)")
        PHASE(1, 1, SA(t + 3, 0, 1) SB(t + 3, 0, 1), "vmcnt(8)")
    }
    {   // peeled last iteration: stage only tile 2NI-1 h1; drain 8->4->0
        const int t = 2 * (NI - 1);
        PHASE(0, 0, SA(t + 1, 1, 1) SB(t + 1, 1, 1), "vmcnt(8)")
        PHASE(0, 1, ((void)0),                       "vmcnt(4)")
        PHASE(1, 0, ((void)0),                       "vmcnt(0)")
        PHASE(1, 1, ((void)0),                       "vmcnt(0)")
    }
#undef PHASE
#undef SA
#undef SB
#undef REGOFF

    // ---------------- epilogue ----------------
    const long cb = QKV ? 0 : (long)z * sC;
    const int row0 = tm * 256 + wr * 128 + (l >> 4) * 4;
    const int col0 = tn * 256 + wc * 64 + rl;

    if (EPI == 0) {
        // LDS-transpose + 16B nontemporal stores (full-line NT, no L3 fill)
        float b4[4];
        #pragma unroll
        for (int n = 0; n < 4; ++n) b4[n] = bias[col0 + n * 16];
        unsigned short* gout = (unsigned short*)Cout;
        #pragma unroll
        for (int half = 0; half < 2; ++half) {
            if (wr == half) {
                #pragma unroll
                for (int mi = 0; mi < 8; ++mi)
                    #pragma unroll
                    for (int n = 0; n < 4; ++n)
                        #pragma unroll
                        for (int r = 0; r < 4; ++r) {
                            const int lr = mi * 16 + ((l >> 4) << 2) + r;
                            const int lc = wc * 64 + n * 16 + rl;
                            lds[lr * 264 + lc] = f2bf(acc[mi][n][r] + b4[n]);
                        }
            }
            __syncthreads();
            const long rbase = (long)(tm * 256 + half * 128);
            #pragma unroll
            for (int rr = 0; rr < 8; ++rr) {
                const int row = rr * 16 + (tid >> 5);
                const int ch = tid & 31;
                short8 vv = *(const short8*)&lds[row * 264 + ch * 8];
                __builtin_nontemporal_store(vv,
                    (short8*)&gout[(rbase + row) * (size_t)ldc + tn * 256 + ch * 8]);
            }
            __syncthreads();
        }
    } else {
        #pragma unroll
        for (int mi = 0; mi < 8; ++mi) {
            #pragma unroll
            for (int n = 0; n < 4; ++n) {
                #pragma unroll
                for (int r = 0; r < 4; ++r) {
                    const int row = row0 + mi * 16 + r;
                    const int col = col0 + n * 16;
                    float v = acc[mi][n][r];
                    if (EPI == 3) v += bias[col];
                    if (EPI == 1) {
                        v *= scale;
                        if (mask[(long)z * sM + (long)row * ldc + col] == 0)
                            v = -1e20f * scale;
                    }
                    if (EPI == 3)   // f32: 16 lanes x 4B = full 64B line -> NT ok
                        __builtin_nontemporal_store(v, &((float*)Cout)[cb + (long)row * ldc + col]);
                    else
                        ((unsigned short*)Cout)[cb + (long)row * ldc + col] = f2bf(v);
                }
            }
        }
    }
}

// ---------------------------------------------------------------------------
// Transpose+cast the four 1280x1280 f32 weights -> Wt[j][k] bf16
// ---------------------------------------------------------------------------
__global__ void transpose_w(const float* __restrict__ Wq, const float* __restrict__ Wk,
                            const float* __restrict__ Wv, const float* __restrict__ Wr,
                            unsigned short* __restrict__ Wt)
{
    const float* W = blockIdx.z == 0 ? Wq : blockIdx.z == 1 ? Wk : blockIdx.z == 2 ? Wv : Wr;
    unsigned short* dst = Wt + (size_t)blockIdx.z * 1280 * 1280;
    __shared__ float T[64][65];
    const int j0 = blockIdx.x * 64, k0 = blockIdx.y * 64;
    const int tid = threadIdx.x;
    for (int it = 0; it < 16; ++it) {
        int idx = it * 256 + tid;
        int r = idx >> 6, c = idx & 63;
        T[r][c] = W[(size_t)(k0 + r) * 1280 + j0 + c];
    }
    __syncthreads();
    for (int it = 0; it < 16; ++it) {
        int idx = it * 256 + tid;
        int r = idx >> 6, c = idx & 63;
        dst[(size_t)(j0 + r) * 1280 + k0 + c] = f2bf(T[c][r]);
    }
}

// ---------------------------------------------------------------------------
// Cast x f32 -> bf16, vectorized
// ---------------------------------------------------------------------------
__global__ void cast_x(const float* __restrict__ x, unsigned short* __restrict__ xb, long n)
{
    long i = ((long)blockIdx.x * 256 + threadIdx.x) * 8;
    if (i + 8 > n) return;
    const float4* p = (const float4*)(x + i);
    float4 a = p[0], b = p[1];
    unsigned short o[8] = { f2bf(a.x), f2bf(a.y), f2bf(a.z), f2bf(a.w),
                            f2bf(b.x), f2bf(b.y), f2bf(b.z), f2bf(b.w) };
    *(short8*)(xb + i) = *(short8*)o;
}

// ---------------------------------------------------------------------------
// Row softmax of scaled+masked scores S'[b][m][n] (bf16) and transposed write
// Pt[b][n][m] = softmax_row(S')[m][n].  One block per (64-row strip, batch).
// ---------------------------------------------------------------------------
#define SMS 514
__global__ void softmax_t(const unsigned short* __restrict__ S, unsigned short* __restrict__ Pt)
{
    __shared__ unsigned short T[64 * SMS];
    __shared__ float rmax[64], rinv[64];
    const int b = blockIdx.y, mb = blockIdx.x * 64;
    const int tid = threadIdx.x, lane = tid & 63, wave = tid >> 6;
    const unsigned short* src = S + ((size_t)b * 512 + mb) * 512;

    for (int rr = 0; rr < 16; ++rr) {
        int r = rr * 4 + wave;
        const unsigned int* s = (const unsigned int*)(src + (size_t)r * 512);
        unsigned int* t = (unsigned int*)&T[r * SMS];
        #pragma unroll
        for (int j = 0; j < 4; ++j) t[lane + j * 64] = s[lane + j * 64];
    }
    __syncthreads();

    {   // row stats: 4 threads per row
        int r = tid >> 2, q = tid & 3;
        const unsigned short* row = &T[r * SMS + q * 128];
        float mx = -3.0e38f;
        for (int i = 0; i < 128; ++i) mx = fmaxf(mx, bf2f(row[i]));
        mx = fmaxf(mx, __shfl_xor(mx, 1));
        mx = fmaxf(mx, __shfl_xor(mx, 2));
        float s = 0.f;
        for (int i = 0; i < 128; ++i) s += expf(bf2f(row[i]) - mx);
        s += __shfl_xor(s, 1);
        s += __shfl_xor(s, 2);
        if (q == 0) { rmax[r] = mx; rinv[r] = 1.0f / s; }
    }
    __syncthreads();

    {   // transposed write: lane -> m, groups of 64 -> n
        int m = tid & 63, nq = tid >> 6;
        float mxm = rmax[m], rim = rinv[m];
        unsigned short* dst = Pt + (size_t)b * 512 * 512 + mb + m;
        for (int it = 0; it < 128; ++it) {
            int n = it * 4 + nq;
            float v = expf(bf2f(T[m * SMS + n]) - mxm) * rim;
            dst[(size_t)n * 512] = f2bf(v);
        }
    }
}

// ---------------------------------------------------------------------------
// Per-batch transpose V[b][m][c] -> Vt[b][c][m]  (bf16)
// ---------------------------------------------------------------------------
__global__ void transpose_v(const unsigned short* __restrict__ V, unsigned short* __restrict__ Vt)
{
    __shared__ unsigned short T[64][65];
    const int b = blockIdx.z;
    const int c0 = blockIdx.x * 64, m0 = blockIdx.y * 64;
    const int tid = threadIdx.x;
    const unsigned short* src = V + ((size_t)b * 512 + m0) * 1280 + c0;
    for (int it = 0; it < 16; ++it) {
        int idx = it * 256 + tid;
        int r = idx >> 6, c = idx & 63;
        T[r][c] = src[(size_t)r * 1280 + c];
    }
    __syncthreads();
    unsigned short* dst = Vt + ((size_t)b * 1280 + c0) * 512 + m0;
    for (int it = 0; it < 16; ++it) {
        int idx = it * 256 + tid;
        int r = idx >> 6, c = idx & 63;
        dst[(size_t)r * 512 + c] = T[c][r];
    }
}

// ---------------------------------------------------------------------------
extern "C" void kernel_launch(void* const* d_in, const int* in_sizes, int n_in,
                              void* d_out, int out_size, void* d_ws, size_t ws_size,
                              hipStream_t stream)
{
    const float* x   = (const float*)d_in[0];
    const int*  Mask = (const int*)d_in[1];
    const float* Wq  = (const float*)d_in[2];
    const float* bq  = (const float*)d_in[3];
    const float* Wk  = (const float*)d_in[4];
    const float* bk  = (const float*)d_in[5];
    const float* Wv  = (const float*)d_in[6];
    const float* bv  = (const float*)d_in[7];
    const float* Wr  = (const float*)d_in[8];
    const float* br  = (const float*)d_in[9];

    constexpr int N = 512, C = 1280;
    constexpr long MN = 32768;   // B*N

    char* ws = (char*)d_ws;
    unsigned short* xb = (unsigned short*)ws;                         // MN*C bf16 (later: att)
    unsigned short* Wt = (unsigned short*)(ws + 83886080);            // 4*C*C bf16
    unsigned short* Q  = (unsigned short*)(ws + 83886080 + 13107200); // MN*C (later: Vt)
    unsigned short* Km = Q + 41943040;
    unsigned short* V  = Km + 41943040;
    unsigned short* Sp = V + 41943040;                                // B*N*N
    unsigned short* Pt = Sp + 16777216;                               // B*N*N
    unsigned short* Vt = Q;     // alias: Q dead after scores GEMM
    unsigned short* att = xb;   // alias: xb dead after QKV GEMMs

    const float scale = 0.02795084971874737f;   // 1/sqrt(1280)

    transpose_w<<<dim3(20, 20, 4), 256, 0, stream>>>(Wq, Wk, Wv, Wr, Wt);
    cast_x<<<dim3(20480), 256, 0, stream>>>(x, xb, MN * C);

    // fused QKV projections: M=32768, N=3x1280, K=1280; tn/5 selects group
    gemm256<0, 1><<<dim3(15, 128, 1), 512, 0, stream>>>(xb, Wt, (void*)Q, bq, bk, bv,
        nullptr, C, C, C, C, 0, 1638400L, 41943040L, 0, 0.f);

    // scores: S'[b][i][j] = scale * (Q[b][i] . K[b][j]), masked
    gemm256<1, 0><<<dim3(2, 2, 64), 512, 0, stream>>>(Q, Km, (void*)Sp, nullptr, nullptr, nullptr,
        Mask, C, C, C, N, (long)N * C, (long)N * C, (long)N * N, (long)N * N, scale);

    // softmax rows + transposed store Pt[b][n][m]
    softmax_t<<<dim3(8, 64), 256, 0, stream>>>(Sp, Pt);

    // Vt[b][c][m]
    transpose_v<<<dim3(20, 8, 64), 256, 0, stream>>>(V, Vt);

    // att[b][n][c] = sum_m Pt[b][n][m] * Vt[b][c][m]   (M=512, N=1280, K=512)
    gemm256<2, 0><<<dim3(5, 2, 64), 512, 0, stream>>>(Pt, Vt, (void*)att, nullptr, nullptr, nullptr,
        nullptr, N, N, N, C, (long)N * N, (long)C * N, (long)N * C, 0, 0.f);

    // out = att @ Wr + br   (f32)
    gemm256<3, 0><<<dim3(5, 128, 1), 512, 0, stream>>>(att, Wt + 3 * 1638400, d_out, br, nullptr, nullptr,
        nullptr, C, C, C, C, 0, 0, 0, 0, 0.f);
}